// Round 5
// baseline (91.766 us; speedup 1.0000x reference)
//
#include <hip/hip_runtime.h>
#include <hip/hip_bf16.h>
#include <hip/hip_cooperative_groups.h>
#include <math.h>

namespace cg = cooperative_groups;

#define D 256
#define BATCH 2048
#define NREL 500
#define NRELP 512
#define CURV_C 0.01f
#define SQRT_C 0.1f

typedef __attribute__((ext_vector_type(8))) short s16x8;
typedef __attribute__((ext_vector_type(4))) float f32x4;

__device__ __forceinline__ float wave_reduce(float v) {
    #pragma unroll
    for (int off = 1; off < 64; off <<= 1) v += __shfl_xor(v, off, 64);
    return v;
}

__device__ __forceinline__ float dot4(float4 a, float4 b) {
    return a.x * b.x + a.y * b.y + a.z * b.z + a.w * b.w;
}

__device__ __forceinline__ float tanh_fast(float x) {
    float e = __expf(2.0f * x);
    return 1.0f - 2.0f / (e + 1.0f);
}
__device__ __forceinline__ float artanh_fast(float z) {
    z = fminf(fmaxf(z, -1.0f + 1e-7f), 1.0f - 1e-7f);
    return 0.5f * __logf((1.0f + z) / (1.0f - z));
}

__device__ __forceinline__ unsigned short f2bf(float x) {
    union { float f; unsigned int u; } c; c.f = x;
    unsigned int r = (c.u + 0x7fffu + ((c.u >> 16) & 1u)) >> 16;
    return (unsigned short)r;
}
__device__ __forceinline__ float bf2f(unsigned short h) {
    union { unsigned int u; float f; } c; c.u = ((unsigned int)h) << 16;
    return c.f;
}

__device__ __forceinline__ void store_hilo(unsigned short* ph, unsigned short* pl, float4 v) {
    ushort4 h, lo;
    #pragma unroll
    for (int e = 0; e < 4; ++e) {
        float x = (&v.x)[e];
        unsigned short hb = f2bf(x);
        float hf = bf2f(hb);
        (&h.x)[e] = hb;
        (&lo.x)[e] = f2bf(x - hf);
    }
    *(ushort4*)ph = h;
    *(ushort4*)pl = lo;
}

// rel row r -> Hh/Hl/r2
__device__ __forceinline__ void do_rel_row(int r, int l, const float* __restrict__ rel,
                                           unsigned short* __restrict__ Hh,
                                           unsigned short* __restrict__ Hl,
                                           float* __restrict__ r2out) {
    float4 v = make_float4(0.f, 0.f, 0.f, 0.f);
    if (r < NREL) v = *(const float4*)&rel[(size_t)r * D + 4 * l];
    float n2 = wave_reduce(dot4(v, v));
    float n = fmaxf(sqrtf(n2), 1e-15f);
    float f = tanh_fast(SQRT_C * n) / (SQRT_C * n);
    float4 hv = make_float4(f * v.x, f * v.y, f * v.z, f * v.w);
    store_hilo(&Hh[(size_t)r * D + 4 * l], &Hl[(size_t)r * D + 4 * l], hv);
    if (l == 0) r2out[r] = f * f * n2;
}

// query row b -> Qh/Ql/q2
__device__ __forceinline__ void do_query_row(int b, int l,
    const float* __restrict__ ent, const int* __restrict__ trip,
    const float* __restrict__ grot, const float* __restrict__ gref,
    const float* __restrict__ attw,
    unsigned short* __restrict__ Qh, unsigned short* __restrict__ Ql,
    float* __restrict__ q2out)
{
    const int s = trip[3 * b + 0];
    const int o = trip[3 * b + 2];
    float4 se = *(const float4*)&ent[(size_t)s * D + 4 * l];
    float4 oe = *(const float4*)&ent[(size_t)o * D + 4 * l];

    float ns2 = wave_reduce(dot4(se, se));
    float no2 = wave_reduce(dot4(oe, oe));
    float ns = fmaxf(sqrtf(ns2), 1e-15f);
    float no = fmaxf(sqrtf(no2), 1e-15f);
    float fs = artanh_fast(SQRT_C * ns) / (SQRT_C * ns);
    float fo = artanh_fast(SQRT_C * no) / (SQRT_C * no);
    float4 st = make_float4(fs * se.x, fs * se.y, fs * se.z, fs * se.w);
    float4 ot = make_float4(fo * oe.x, fo * oe.y, fo * oe.z, fo * oe.w);

    float4 wa = *(const float4*)&attw[4 * l];
    float4 wb = *(const float4*)&attw[D + 4 * l];
    float adot = wave_reduce(dot4(st, wa) + dot4(ot, wb));
    float a = 1.0f / (1.0f + __expf(-adot));

    float2 ar = ((const float2*)grot)[l];
    float2 af = ((const float2*)gref)[l];
    float ca0 = __cosf(ar.x), sa0 = __sinf(ar.x);
    float ca1 = __cosf(ar.y), sa1 = __sinf(ar.y);
    float cr0 = __cosf(af.x), sr0 = __sinf(af.x);
    float cr1 = __cosf(af.y), sr1 = __sinf(af.y);

    float4 rot = make_float4(ca0 * st.x - sa0 * st.y, sa0 * st.x + ca0 * st.y,
                             ca1 * st.z - sa1 * st.w, sa1 * st.z + ca1 * st.w);
    float4 rfl = make_float4(cr0 * st.x + sr0 * st.y, sr0 * st.x - cr0 * st.y,
                             cr1 * st.z + sr1 * st.w, sr1 * st.z - cr1 * st.w);
    float ia = 1.0f - a;
    float4 mt = make_float4(a * rot.x + ia * rfl.x, a * rot.y + ia * rfl.y,
                            a * rot.z + ia * rfl.z, a * rot.w + ia * rfl.w);

    float nm2 = wave_reduce(dot4(mt, mt));
    float nm = fmaxf(sqrtf(nm2), 1e-15f);
    float fm = tanh_fast(SQRT_C * nm) / (SQRT_C * nm);
    float4 mh = make_float4(fm * mt.x, fm * mt.y, fm * mt.z, fm * mt.w);
    float x2v = fm * fm * nm2;

    float xy = wave_reduce(-dot4(mh, oe));
    const float c = CURV_C;
    float A  = 1.0f + 2.0f * c * xy + c * no2;
    float Bf = 1.0f - c * x2v;
    float den = fmaxf(1.0f + 2.0f * c * xy + c * c * x2v * no2, 1e-15f);
    float inv = 1.0f / den;
    float4 q = make_float4((A * -mh.x + Bf * oe.x) * inv,
                           (A * -mh.y + Bf * oe.y) * inv,
                           (A * -mh.z + Bf * oe.z) * inv,
                           (A * -mh.w + Bf * oe.w) * inv);
    store_hilo(&Qh[(size_t)b * D + 4 * l], &Ql[(size_t)b * D + 4 * l], q);
    if (l == 0) {
        float num2 = A * A * x2v + 2.0f * A * Bf * xy + Bf * Bf * no2;
        q2out[b] = num2 * inv * inv;
    }
}

// ---------------- fused cooperative kernel ----------------
// grid 256 x 512thr, 128KB LDS -> 1 block/CU, all co-resident.
// Phase 1: wave gw computes query row gw; waves gw<512 also rel row gw.
// grid.sync()
// Phase 2: block bx scores m-tile (bx&31), n-tile (bx>>5).
__global__ __launch_bounds__(512) void fused_kernel(
    const float* __restrict__ ent, const float* __restrict__ rel,
    const int* __restrict__ trip,
    const float* __restrict__ grot, const float* __restrict__ gref,
    const float* __restrict__ attw, const float* __restrict__ bias,
    float* __restrict__ out,
    unsigned short* __restrict__ Qh, unsigned short* __restrict__ Ql,
    float* __restrict__ q2,
    unsigned short* __restrict__ Hh, unsigned short* __restrict__ Hl,
    float* __restrict__ r2)
{
    __shared__ __align__(16) unsigned char lds[131072];
    const int t = threadIdx.x;
    const int bx = blockIdx.x;
    const int w = t >> 6;
    const int l = t & 63;

    // ---- phase 1
    {
        const int gw = bx * 8 + w;          // 0..2047
        do_query_row(gw, l, ent, trip, grot, gref, attw, Qh, Ql, q2);
        if (gw < NRELP) do_rel_row(gw, l, rel, Hh, Hl, r2);
    }
    __threadfence();
    cg::this_grid().sync();

    // ---- phase 2
    const int m0 = (bx & 31) * 64, n0 = (bx >> 5) * 64;

    // stage: wave w fills rows [w*8, w*8+8) of all four 32KB arrays.
    {
        const int rsub = l >> 5;
        const int cl = l & 31;
        #pragma unroll
        for (int it = 0; it < 4; ++it) {
            const int r = w * 8 + it * 2 + rsub;
            const unsigned int csw = (unsigned int)((cl ^ (r & 7)) * 8);
            const unsigned int loff = (unsigned int)(w * 4096 + it * 1024);
            const size_t gA = (size_t)(m0 + r) * D + csw;
            const size_t gB = (size_t)(n0 + r) * D + csw;
            __builtin_amdgcn_global_load_lds(
                (const __attribute__((address_space(1))) void*)(Qh + gA),
                (__attribute__((address_space(3))) void*)(lds + loff), 16, 0, 0);
            __builtin_amdgcn_global_load_lds(
                (const __attribute__((address_space(1))) void*)(Ql + gA),
                (__attribute__((address_space(3))) void*)(lds + 32768 + loff), 16, 0, 0);
            __builtin_amdgcn_global_load_lds(
                (const __attribute__((address_space(1))) void*)(Hh + gB),
                (__attribute__((address_space(3))) void*)(lds + 65536 + loff), 16, 0, 0);
            __builtin_amdgcn_global_load_lds(
                (const __attribute__((address_space(1))) void*)(Hl + gB),
                (__attribute__((address_space(3))) void*)(lds + 98304 + loff), 16, 0, 0);
        }
    }
    __syncthreads();

    const int wm = w >> 2;
    const int wn = w & 3;
    const int lr = l & 15;
    const int lk = l >> 4;
    const unsigned int sw = (unsigned int)((lr & 7) << 4);

    f32x4 acc[2];
    acc[0] = (f32x4){0.f, 0.f, 0.f, 0.f};
    acc[1] = (f32x4){0.f, 0.f, 0.f, 0.f};

    const unsigned int bbase = (unsigned int)((wn * 16 + lr) * 512);
    const unsigned int abase = (unsigned int)((wm * 32 + lr) * 512);
    #pragma unroll
    for (int ks = 0; ks < 8; ++ks) {
        const unsigned int coff = ((unsigned int)(ks * 4 + lk) << 4) ^ sw;
        s16x8 bh = *(const s16x8*)(lds + 65536 + bbase + coff);
        s16x8 bl = *(const s16x8*)(lds + 98304 + bbase + coff);
        #pragma unroll
        for (int mi = 0; mi < 2; ++mi) {
            const unsigned int aoff = abase + (unsigned int)(mi * 16 * 512) + coff;
            s16x8 ah = *(const s16x8*)(lds + aoff);
            s16x8 al = *(const s16x8*)(lds + 32768 + aoff);
            acc[mi] = __builtin_amdgcn_mfma_f32_16x16x32_bf16(ah, bh, acc[mi], 0, 0, 0);
            acc[mi] = __builtin_amdgcn_mfma_f32_16x16x32_bf16(ah, bl, acc[mi], 0, 0, 0);
            acc[mi] = __builtin_amdgcn_mfma_f32_16x16x32_bf16(al, bh, acc[mi], 0, 0, 0);
        }
    }

    const int n = n0 + wn * 16 + lr;
    const bool nok = (n < NREL);
    float y2v = 0.f, biasv = 0.f;
    if (nok) { y2v = r2[n]; biasv = bias[n]; }
    const float c = CURV_C;
    #pragma unroll
    for (int mi = 0; mi < 2; ++mi) {
        #pragma unroll
        for (int rg = 0; rg < 4; ++rg) {
            const int m = m0 + wm * 32 + mi * 16 + lk * 4 + rg;
            const float x2 = q2[m];
            const float Bf = 1.0f - c * x2;
            const float xy = -acc[mi][rg];
            const float A  = 1.0f + 2.0f * c * xy + c * y2v;
            const float den = fmaxf(1.0f + 2.0f * c * xy + c * c * x2 * y2v, 1e-15f);
            const float num2 = A * A * x2 + 2.0f * A * Bf * xy + Bf * Bf * y2v;
            if (nok) out[(size_t)m * NREL + n] = biasv - num2 / (den * den);
        }
    }
}

extern "C" void kernel_launch(void* const* d_in, const int* in_sizes, int n_in,
                              void* d_out, int out_size, void* d_ws, size_t ws_size,
                              hipStream_t stream) {
    const float* ent  = (const float*)d_in[0];   // 20000 x 256
    const float* rel  = (const float*)d_in[1];   // 500 x 256
    const int*   trip = (const int*)d_in[2];     // 2048 x 3
    const float* grot = (const float*)d_in[3];   // 128
    const float* gref = (const float*)d_in[4];   // 128
    const float* attw = (const float*)d_in[5];   // 512
    const float* bias = (const float*)d_in[6];   // 500
    float* out = (float*)d_out;                  // 2048 x 500

    char* ws = (char*)d_ws;
    unsigned short* Qh = (unsigned short*)(ws);                       // 1 MB
    unsigned short* Ql = (unsigned short*)(ws + (1u << 20));          // 1 MB
    unsigned short* Hh = (unsigned short*)(ws + (2u << 20));          // 256 KB
    unsigned short* Hl = (unsigned short*)(ws + (2u << 20) + (256u << 10)); // 256 KB
    float* q2 = (float*)(ws + (2u << 20) + (512u << 10));             // 8 KB
    float* r2 = (float*)(ws + (2u << 20) + (512u << 10) + 8192);      // 2 KB

    void* args[] = { (void*)&ent, (void*)&rel, (void*)&trip, (void*)&grot,
                     (void*)&gref, (void*)&attw, (void*)&bias, (void*)&out,
                     (void*)&Qh, (void*)&Ql, (void*)&q2,
                     (void*)&Hh, (void*)&Hl, (void*)&r2 };
    hipLaunchCooperativeKernel((void*)fused_kernel, dim3(256), dim3(512),
                               args, 0, stream);
}

// Round 6
// 28.111 us; speedup vs baseline: 3.2644x; 3.2644x over previous
//
#include <hip/hip_runtime.h>
#include <hip/hip_bf16.h>
#include <math.h>

#define D 256
#define BATCH 2048
#define NREL 500
#define CURV_C 0.01f
#define SQRT_C 0.1f

typedef __attribute__((ext_vector_type(8))) short s16x8;
typedef __attribute__((ext_vector_type(4))) float f32x4;

__device__ __forceinline__ float dot4(float4 a, float4 b) {
    return a.x * b.x + a.y * b.y + a.z * b.z + a.w * b.w;
}

__device__ __forceinline__ float wave_reduce1(float a) {
    #pragma unroll
    for (int off = 1; off < 64; off <<= 1) a += __shfl_xor(a, off, 64);
    return a;
}
__device__ __forceinline__ void wave_reduce2(float& a, float& b) {
    #pragma unroll
    for (int off = 1; off < 64; off <<= 1) {
        a += __shfl_xor(a, off, 64);
        b += __shfl_xor(b, off, 64);
    }
}
__device__ __forceinline__ void wave_reduce4(float& a, float& b, float& c, float& d) {
    #pragma unroll
    for (int off = 1; off < 64; off <<= 1) {
        a += __shfl_xor(a, off, 64);
        b += __shfl_xor(b, off, 64);
        c += __shfl_xor(c, off, 64);
        d += __shfl_xor(d, off, 64);
    }
}

__device__ __forceinline__ float tanh_fast(float x) {
    float e = __expf(2.0f * x);
    return 1.0f - 2.0f / (e + 1.0f);
}
__device__ __forceinline__ float artanh_fast(float z) {
    z = fminf(fmaxf(z, -1.0f + 1e-7f), 1.0f - 1e-7f);
    return 0.5f * __logf((1.0f + z) / (1.0f - z));
}

__device__ __forceinline__ unsigned short f2bf(float x) {
    union { float f; unsigned int u; } c; c.f = x;
    unsigned int r = (c.u + 0x7fffu + ((c.u >> 16) & 1u)) >> 16;
    return (unsigned short)r;
}
__device__ __forceinline__ float bf2f(unsigned short h) {
    union { unsigned int u; float f; } c; c.u = ((unsigned int)h) << 16;
    return c.f;
}
__device__ __forceinline__ void pack_hilo(float4 v, ushort4& h, ushort4& lo) {
    #pragma unroll
    for (int e = 0; e < 4; ++e) {
        float x = (&v.x)[e];
        unsigned short hb = f2bf(x);
        (&h.x)[e] = hb;
        (&lo.x)[e] = f2bf(x - bf2f(hb));
    }
}

// ---------------- fully fused, no grid sync, no workspace ----------------
// grid 256 = 32 m-tiles x 8 n-tiles; 512 thr; 1 block/CU (128KB+ LDS).
// Each block computes its 64 Q rows + 64 H rows straight into swizzled LDS,
// one __syncthreads, then the bf16 hi/lo triple-MFMA score tile.
// LDS layout (per array, 64 rows x 512B): LDS chunk s of row r holds global
// 16B-chunk s ^ (r&7). Ah @0, Al @32768, Bh @65536, Bl @98304.
__global__ __launch_bounds__(512, 2) void fused_kernel(
    const float* __restrict__ ent, const float* __restrict__ rel,
    const int* __restrict__ trip,
    const float* __restrict__ grot, const float* __restrict__ gref,
    const float* __restrict__ attw, const float* __restrict__ bias,
    float* __restrict__ out)
{
    __shared__ __align__(16) unsigned char lds[131072];
    __shared__ float q2s[64];
    __shared__ float r2s[64];

    const int t = threadIdx.x;
    const int bx = blockIdx.x;
    const int w = t >> 6, l = t & 63;
    const int m0 = (bx & 31) * 64;
    const int n0 = (bx >> 5) * 64;

    // per-lane constants hoisted out of the row loops
    const float4 wa = *(const float4*)&attw[4 * l];
    const float4 wb = *(const float4*)&attw[D + 4 * l];
    const float2 ar = ((const float2*)grot)[l];
    const float2 af = ((const float2*)gref)[l];
    const float ca0 = __cosf(ar.x), sa0 = __sinf(ar.x);
    const float ca1 = __cosf(ar.y), sa1 = __sinf(ar.y);
    const float cr0 = __cosf(af.x), sr0 = __sinf(af.x);
    const float cr1 = __cosf(af.y), sr1 = __sinf(af.y);

    // swizzled 8B slot for this lane within a row
    // byte_off(r) = r*512 + (((l>>1) ^ (r&7))<<4) + (l&1)*8
    const unsigned ch = (unsigned)(l >> 1);
    const unsigned sub8 = (unsigned)((l & 1) * 8);

    // ---- prefetch the Q gathers for my 8 rows (long-latency, issue early)
    float4 se8[8], oe8[8];
    #pragma unroll
    for (int i = 0; i < 8; ++i) {
        const int b = m0 + w * 8 + i;
        const int s = trip[3 * b + 0];
        const int o = trip[3 * b + 2];
        se8[i] = *(const float4*)&ent[(size_t)s * D + 4 * l];
        oe8[i] = *(const float4*)&ent[(size_t)o * D + 4 * l];
    }

    // ---- H rows (hide gather latency under this)
    #pragma unroll
    for (int i = 0; i < 8; ++i) {
        const int r = w * 8 + i;               // local n row
        const int gn = n0 + r;
        float4 v = make_float4(0.f, 0.f, 0.f, 0.f);
        if (gn < NREL) v = *(const float4*)&rel[(size_t)gn * D + 4 * l];
        float n2 = wave_reduce1(dot4(v, v));
        float nn = fmaxf(sqrtf(n2), 1e-15f);
        float f = tanh_fast(SQRT_C * nn) / (SQRT_C * nn);
        float4 hv = make_float4(f * v.x, f * v.y, f * v.z, f * v.w);
        ushort4 h, lo; pack_hilo(hv, h, lo);
        const unsigned off = (unsigned)(r * 512) + ((ch ^ (unsigned)(r & 7)) << 4) + sub8;
        *(ushort4*)(lds + 65536 + off) = h;
        *(ushort4*)(lds + 98304 + off) = lo;
        if (l == 0) r2s[r] = f * f * n2;
    }

    // ---- Q rows: 2 packed reduction chains per row
    #pragma unroll
    for (int i = 0; i < 8; ++i) {
        const int r = w * 8 + i;               // local m row
        const float4 se = se8[i], oe = oe8[i];
        float ns2 = dot4(se, se), no2 = dot4(oe, oe);
        float dsw = dot4(se, wa), dow = dot4(oe, wb);
        wave_reduce4(ns2, no2, dsw, dow);
        const float ns = fmaxf(sqrtf(ns2), 1e-15f);
        const float no = fmaxf(sqrtf(no2), 1e-15f);
        const float fs = artanh_fast(SQRT_C * ns) / (SQRT_C * ns);
        const float fo = artanh_fast(SQRT_C * no) / (SQRT_C * no);
        const float adot = fs * dsw + fo * dow;
        const float a = 1.0f / (1.0f + __expf(-adot));
        const float4 st = make_float4(fs * se.x, fs * se.y, fs * se.z, fs * se.w);
        const float4 rot = make_float4(ca0 * st.x - sa0 * st.y, sa0 * st.x + ca0 * st.y,
                                       ca1 * st.z - sa1 * st.w, sa1 * st.z + ca1 * st.w);
        const float4 rfl = make_float4(cr0 * st.x + sr0 * st.y, sr0 * st.x - cr0 * st.y,
                                       cr1 * st.z + sr1 * st.w, sr1 * st.z - cr1 * st.w);
        const float ia = 1.0f - a;
        const float4 mt = make_float4(a * rot.x + ia * rfl.x, a * rot.y + ia * rfl.y,
                                      a * rot.z + ia * rfl.z, a * rot.w + ia * rfl.w);
        float nm2 = dot4(mt, mt), mtoe = dot4(mt, oe);
        wave_reduce2(nm2, mtoe);
        const float nm = fmaxf(sqrtf(nm2), 1e-15f);
        const float fm = tanh_fast(SQRT_C * nm) / (SQRT_C * nm);
        const float x2v = fm * fm * nm2;
        const float xy = -fm * mtoe;
        const float c = CURV_C;
        const float A  = 1.0f + 2.0f * c * xy + c * no2;
        const float Bf = 1.0f - c * x2v;
        const float den = fmaxf(1.0f + 2.0f * c * xy + c * c * x2v * no2, 1e-15f);
        const float inv = 1.0f / den;
        const float Afm = A * fm;
        const float4 q = make_float4((Bf * oe.x - Afm * mt.x) * inv,
                                     (Bf * oe.y - Afm * mt.y) * inv,
                                     (Bf * oe.z - Afm * mt.z) * inv,
                                     (Bf * oe.w - Afm * mt.w) * inv);
        ushort4 h, lo; pack_hilo(q, h, lo);
        const unsigned off = (unsigned)(r * 512) + ((ch ^ (unsigned)(r & 7)) << 4) + sub8;
        *(ushort4*)(lds + off) = h;
        *(ushort4*)(lds + 32768 + off) = lo;
        if (l == 0) {
            const float num2 = A * A * x2v + 2.0f * A * Bf * xy + Bf * Bf * no2;
            q2s[r] = num2 * inv * inv;
        }
    }

    __syncthreads();

    // ---- MFMA phase: wave (wm, wn) owns 32m x 16n strip
    const int wm = w >> 2;
    const int wn = w & 3;
    const int lr = l & 15;
    const int lk = l >> 4;
    const unsigned sw = (unsigned)((lr & 7) << 4);

    f32x4 acc[2];
    acc[0] = (f32x4){0.f, 0.f, 0.f, 0.f};
    acc[1] = (f32x4){0.f, 0.f, 0.f, 0.f};

    const unsigned bbase = (unsigned)((wn * 16 + lr) * 512);
    const unsigned abase = (unsigned)((wm * 32 + lr) * 512);
    #pragma unroll
    for (int ks = 0; ks < 8; ++ks) {
        const unsigned coff = ((unsigned)(ks * 4 + lk) << 4) ^ sw;
        s16x8 bh = *(const s16x8*)(lds + 65536 + bbase + coff);
        s16x8 bl = *(const s16x8*)(lds + 98304 + bbase + coff);
        #pragma unroll
        for (int mi = 0; mi < 2; ++mi) {
            const unsigned aoff = abase + (unsigned)(mi * 16 * 512) + coff;
            s16x8 ah = *(const s16x8*)(lds + aoff);
            s16x8 al = *(const s16x8*)(lds + 32768 + aoff);
            acc[mi] = __builtin_amdgcn_mfma_f32_16x16x32_bf16(ah, bh, acc[mi], 0, 0, 0);
            acc[mi] = __builtin_amdgcn_mfma_f32_16x16x32_bf16(ah, bl, acc[mi], 0, 0, 0);
            acc[mi] = __builtin_amdgcn_mfma_f32_16x16x32_bf16(al, bh, acc[mi], 0, 0, 0);
        }
    }

    // ---- epilogue: C layout col(n)=lane&15, row(m)=(lane>>4)*4+reg
    const int nl = wn * 16 + lr;
    const int n = n0 + nl;
    const bool nok = (n < NREL);
    float y2v = r2s[nl];
    float biasv = nok ? bias[n] : 0.f;
    const float c = CURV_C;
    #pragma unroll
    for (int mi = 0; mi < 2; ++mi) {
        #pragma unroll
        for (int rg = 0; rg < 4; ++rg) {
            const int ml = wm * 32 + mi * 16 + lk * 4 + rg;
            const int m = m0 + ml;
            const float x2 = q2s[ml];
            const float Bf = 1.0f - c * x2;
            const float xy = -acc[mi][rg];
            const float A  = 1.0f + 2.0f * c * xy + c * y2v;
            const float den = fmaxf(1.0f + 2.0f * c * xy + c * c * x2 * y2v, 1e-15f);
            const float num2 = A * A * x2 + 2.0f * A * Bf * xy + Bf * Bf * y2v;
            if (nok) out[(size_t)m * NREL + n] = biasv - num2 / (den * den);
        }
    }
}

extern "C" void kernel_launch(void* const* d_in, const int* in_sizes, int n_in,
                              void* d_out, int out_size, void* d_ws, size_t ws_size,
                              hipStream_t stream) {
    const float* ent  = (const float*)d_in[0];   // 20000 x 256
    const float* rel  = (const float*)d_in[1];   // 500 x 256
    const int*   trip = (const int*)d_in[2];     // 2048 x 3
    const float* grot = (const float*)d_in[3];   // 128
    const float* gref = (const float*)d_in[4];   // 128
    const float* attw = (const float*)d_in[5];   // 512
    const float* bias = (const float*)d_in[6];   // 500
    float* out = (float*)d_out;                  // 2048 x 500

    fused_kernel<<<256, 512, 0, stream>>>(ent, rel, trip, grot, gref, attw, bias, out);
}

// Round 7
// 17.523 us; speedup vs baseline: 5.2370x; 1.6042x over previous
//
#include <hip/hip_runtime.h>
#include <hip/hip_bf16.h>
#include <math.h>

#define D 256
#define BATCH 2048
#define NREL 500
#define NRELP 512
#define CURV_C 0.01f
#define SQRT_C 0.1f

typedef __attribute__((ext_vector_type(8))) short s16x8;
typedef __attribute__((ext_vector_type(4))) float f32x4;

__device__ __forceinline__ float dot4(float4 a, float4 b) {
    return a.x * b.x + a.y * b.y + a.z * b.z + a.w * b.w;
}

__device__ __forceinline__ float wave_reduce1(float a) {
    #pragma unroll
    for (int off = 1; off < 64; off <<= 1) a += __shfl_xor(a, off, 64);
    return a;
}
__device__ __forceinline__ void wave_reduce2(float& a, float& b) {
    #pragma unroll
    for (int off = 1; off < 64; off <<= 1) {
        a += __shfl_xor(a, off, 64);
        b += __shfl_xor(b, off, 64);
    }
}
__device__ __forceinline__ void wave_reduce4(float& a, float& b, float& c, float& d) {
    #pragma unroll
    for (int off = 1; off < 64; off <<= 1) {
        a += __shfl_xor(a, off, 64);
        b += __shfl_xor(b, off, 64);
        c += __shfl_xor(c, off, 64);
        d += __shfl_xor(d, off, 64);
    }
}

__device__ __forceinline__ float tanh_fast(float x) {
    float e = __expf(2.0f * x);
    return 1.0f - 2.0f / (e + 1.0f);
}
__device__ __forceinline__ float artanh_fast(float z) {
    z = fminf(fmaxf(z, -1.0f + 1e-7f), 1.0f - 1e-7f);
    return 0.5f * __logf((1.0f + z) / (1.0f - z));
}

__device__ __forceinline__ unsigned short f2bf(float x) {
    union { float f; unsigned int u; } c; c.f = x;
    unsigned int r = (c.u + 0x7fffu + ((c.u >> 16) & 1u)) >> 16;
    return (unsigned short)r;
}
__device__ __forceinline__ ushort4 pack_bf4(float4 v) {
    ushort4 h;
    h.x = f2bf(v.x); h.y = f2bf(v.y); h.z = f2bf(v.z); h.w = f2bf(v.w);
    return h;
}

// ---------------- prep: wave-per-row, packed reduction chains ----------------
// waves [0, NRELP)           -> Hh (bf16 rows, zero-padded) + r2
// waves [NRELP, NRELP+BATCH) -> Qh (bf16 rows) + q2
__global__ __launch_bounds__(256) void prep_kernel(
    const float* __restrict__ ent, const float* __restrict__ rel,
    const int* __restrict__ trip,
    const float* __restrict__ grot, const float* __restrict__ gref,
    const float* __restrict__ attw,
    unsigned short* __restrict__ Qh, float* __restrict__ q2out,
    unsigned short* __restrict__ Hh, float* __restrict__ r2out)
{
    const int w = blockIdx.x * 4 + (threadIdx.x >> 6);
    const int l = threadIdx.x & 63;

    if (w < NRELP) {
        const int r = w;
        float4 v = make_float4(0.f, 0.f, 0.f, 0.f);
        if (r < NREL) v = *(const float4*)&rel[(size_t)r * D + 4 * l];
        float n2 = wave_reduce1(dot4(v, v));
        float n = fmaxf(sqrtf(n2), 1e-15f);
        float f = tanh_fast(SQRT_C * n) / (SQRT_C * n);
        float4 hv = make_float4(f * v.x, f * v.y, f * v.z, f * v.w);
        *(ushort4*)&Hh[(size_t)r * D + 4 * l] = pack_bf4(hv);
        if (l == 0) r2out[r] = f * f * n2;
    } else if (w < NRELP + BATCH) {
        const int b = w - NRELP;
        const int s = trip[3 * b + 0];
        const int o = trip[3 * b + 2];
        float4 se = *(const float4*)&ent[(size_t)s * D + 4 * l];
        float4 oe = *(const float4*)&ent[(size_t)o * D + 4 * l];

        const float4 wa = *(const float4*)&attw[4 * l];
        const float4 wb = *(const float4*)&attw[D + 4 * l];
        float ns2 = dot4(se, se), no2 = dot4(oe, oe);
        float dsw = dot4(se, wa), dow = dot4(oe, wb);
        wave_reduce4(ns2, no2, dsw, dow);

        const float ns = fmaxf(sqrtf(ns2), 1e-15f);
        const float no = fmaxf(sqrtf(no2), 1e-15f);
        const float fs = artanh_fast(SQRT_C * ns) / (SQRT_C * ns);
        const float fo = artanh_fast(SQRT_C * no) / (SQRT_C * no);
        const float a = 1.0f / (1.0f + __expf(-(fs * dsw + fo * dow)));

        const float4 st = make_float4(fs * se.x, fs * se.y, fs * se.z, fs * se.w);
        const float2 ar = ((const float2*)grot)[l];
        const float2 af = ((const float2*)gref)[l];
        const float ca0 = __cosf(ar.x), sa0 = __sinf(ar.x);
        const float ca1 = __cosf(ar.y), sa1 = __sinf(ar.y);
        const float cr0 = __cosf(af.x), sr0 = __sinf(af.x);
        const float cr1 = __cosf(af.y), sr1 = __sinf(af.y);
        const float4 rot = make_float4(ca0 * st.x - sa0 * st.y, sa0 * st.x + ca0 * st.y,
                                       ca1 * st.z - sa1 * st.w, sa1 * st.z + ca1 * st.w);
        const float4 rfl = make_float4(cr0 * st.x + sr0 * st.y, sr0 * st.x - cr0 * st.y,
                                       cr1 * st.z + sr1 * st.w, sr1 * st.z - cr1 * st.w);
        const float ia = 1.0f - a;
        const float4 mt = make_float4(a * rot.x + ia * rfl.x, a * rot.y + ia * rfl.y,
                                      a * rot.z + ia * rfl.z, a * rot.w + ia * rfl.w);

        float nm2 = dot4(mt, mt), mtoe = dot4(mt, oe);
        wave_reduce2(nm2, mtoe);
        const float nm = fmaxf(sqrtf(nm2), 1e-15f);
        const float fm = tanh_fast(SQRT_C * nm) / (SQRT_C * nm);
        const float x2v = fm * fm * nm2;
        const float xy = -fm * mtoe;

        const float c = CURV_C;
        const float A  = 1.0f + 2.0f * c * xy + c * no2;
        const float Bf = 1.0f - c * x2v;
        const float den = fmaxf(1.0f + 2.0f * c * xy + c * c * x2v * no2, 1e-15f);
        const float inv = 1.0f / den;
        const float Afm = A * fm;
        const float4 q = make_float4((Bf * oe.x - Afm * mt.x) * inv,
                                     (Bf * oe.y - Afm * mt.y) * inv,
                                     (Bf * oe.z - Afm * mt.z) * inv,
                                     (Bf * oe.w - Afm * mt.w) * inv);
        *(ushort4*)&Qh[(size_t)b * D + 4 * l] = pack_bf4(q);
        if (l == 0) {
            const float num2 = A * A * x2v + 2.0f * A * Bf * xy + Bf * Bf * no2;
            q2out[b] = num2 * inv * inv;
        }
    }
}

// ---------------- score: zero-LDS MFMA, fragments straight from L2 ----------------
// grid (32, 8), 512 thr. Wave (wm, wn) owns 32m x 16n of the 64x64 tile.
// A-frag: lane(lr,lk) reads Qh[(m0+wm*32+mi*16+lr)*256 + ks*32 + lk*8] (16B)
// B-frag: lane(lr,lk) reads Hh[(n0+wn*16+lr)*256 + ks*32 + lk*8]       (16B)
__global__ __launch_bounds__(512) void score_kernel(
    const unsigned short* __restrict__ Qh, const float* __restrict__ q2,
    const unsigned short* __restrict__ Hh, const float* __restrict__ r2,
    const float* __restrict__ bias, float* __restrict__ out)
{
    const int t = threadIdx.x;
    const int w = t >> 6, l = t & 63;
    const int wm = w >> 2, wn = w & 3;
    const int lr = l & 15, lk = l >> 4;
    const int m0 = blockIdx.x * 64, n0 = blockIdx.y * 64;

    const unsigned short* Arow0 = Qh + (size_t)(m0 + wm * 32 + lr) * D + lk * 8;
    const unsigned short* Arow1 = Arow0 + 16 * D;
    const unsigned short* Brow  = Hh + (size_t)(n0 + wn * 16 + lr) * D + lk * 8;

    f32x4 acc0 = (f32x4){0.f, 0.f, 0.f, 0.f};
    f32x4 acc1 = (f32x4){0.f, 0.f, 0.f, 0.f};

    #pragma unroll
    for (int ks = 0; ks < 8; ++ks) {
        s16x8 b  = *(const s16x8*)(Brow  + ks * 32);
        s16x8 a0 = *(const s16x8*)(Arow0 + ks * 32);
        s16x8 a1 = *(const s16x8*)(Arow1 + ks * 32);
        acc0 = __builtin_amdgcn_mfma_f32_16x16x32_bf16(a0, b, acc0, 0, 0, 0);
        acc1 = __builtin_amdgcn_mfma_f32_16x16x32_bf16(a1, b, acc1, 0, 0, 0);
    }

    // epilogue: C layout col(n)=lane&15, row(m)=(lane>>4)*4+reg
    const int n = n0 + wn * 16 + lr;
    const bool nok = (n < NREL);
    float y2v = nok ? r2[n] : 0.f;
    float biasv = nok ? bias[n] : 0.f;
    const float c = CURV_C;
    #pragma unroll
    for (int mi = 0; mi < 2; ++mi) {
        const f32x4 acc = mi ? acc1 : acc0;
        #pragma unroll
        for (int rg = 0; rg < 4; ++rg) {
            const int m = m0 + wm * 32 + mi * 16 + lk * 4 + rg;
            const float x2 = q2[m];
            const float Bf = 1.0f - c * x2;
            const float xy = -acc[rg];
            const float A  = 1.0f + 2.0f * c * xy + c * y2v;
            const float den = fmaxf(1.0f + 2.0f * c * xy + c * c * x2 * y2v, 1e-15f);
            const float num2 = A * A * x2 + 2.0f * A * Bf * xy + Bf * Bf * y2v;
            if (nok) out[(size_t)m * NREL + n] = biasv - num2 / (den * den);
        }
    }
}

extern "C" void kernel_launch(void* const* d_in, const int* in_sizes, int n_in,
                              void* d_out, int out_size, void* d_ws, size_t ws_size,
                              hipStream_t stream) {
    const float* ent  = (const float*)d_in[0];   // 20000 x 256
    const float* rel  = (const float*)d_in[1];   // 500 x 256
    const int*   trip = (const int*)d_in[2];     // 2048 x 3
    const float* grot = (const float*)d_in[3];   // 128
    const float* gref = (const float*)d_in[4];   // 128
    const float* attw = (const float*)d_in[5];   // 512
    const float* bias = (const float*)d_in[6];   // 500
    float* out = (float*)d_out;                  // 2048 x 500

    char* ws = (char*)d_ws;
    unsigned short* Qh = (unsigned short*)(ws);                       // 1 MB
    unsigned short* Hh = (unsigned short*)(ws + (1u << 20));          // 256 KB
    float* q2 = (float*)(ws + (1u << 20) + (256u << 10));             // 8 KB
    float* r2 = (float*)(ws + (1u << 20) + (256u << 10) + 8192);      // 2 KB

    const int nwaves = NRELP + BATCH;            // 2560
    prep_kernel<<<nwaves / 4, 256, 0, stream>>>(ent, rel, trip, grot, gref, attw,
                                                Qh, q2, Hh, r2);
    dim3 grid(BATCH / 64, NRELP / 64);
    score_kernel<<<grid, 512, 0, stream>>>(Qh, q2, Hh, r2, bias, out);
}